// Round 1
// baseline (523.637 us; speedup 1.0000x reference)
//
#include <hip/hip_runtime.h>
#include <math.h>

#define NB 256
#define TT 4096
#define HH 32
#define CH 64   // timestep chunk: obuf columns, x-vector window

#if __has_builtin(__builtin_amdgcn_exp2f)
#define EXP2F(x) __builtin_amdgcn_exp2f(x)
#else
#define EXP2F(x) exp2f(x)
#endif

// One wave (64 threads) per batch element. lane = p*32 + h, p splits the
// K-dim of the 32x32 matvec (16 FMAs/lane/step). h vector lives in LDS and
// is read back as broadcast float4s (conflict-free). tanh is computed as
// 1 - 2/(1 + exp2(s)) with the 2*log2(e) factor pre-folded into all weights
// feeding the preactivation. Per-step h is stashed in LDS (stride-65 rows,
// conflict-free) and the W_fc reduction over 64 steps is done in parallel
// across lanes, then stored coalesced.
__global__ __launch_bounds__(64, 1) void rnn_fused(
    const float* __restrict__ x,      // [B,T] (I==1)
    const float* __restrict__ W_ih,   // [H,1]
    const float* __restrict__ W_hh,   // [H,H]
    const float* __restrict__ b_ih,   // [H]
    const float* __restrict__ b_hh,   // [H]
    const float* __restrict__ W_fc,   // [1,H]
    const float* __restrict__ b_fc,   // [1]
    float* __restrict__ out)          // [B,T]
{
    const int lane = threadIdx.x;   // 0..63
    const int h    = lane & 31;
    const int p    = lane >> 5;
    const int b    = blockIdx.x;

    __shared__ float h_lds[64];         // h vector (first 32 entries live)
    __shared__ float obuf[64 * 65];     // [row=lane][col=tc], stride 65 floats

    const float KAPPA = 2.8853900817779268f;  // 2 * log2(e)

    // per-lane slice of W_hh row h, K-half p, pre-scaled by KAPPA
    float W2[16];
#pragma unroll
    for (int r = 0; r < 16; ++r)
        W2[r] = KAPPA * W_hh[h * HH + p * 16 + r];

    // halved so that summing both p-halves yields the xp term exactly once
    const float wihH  = 0.5f * KAPPA * W_ih[h];
    const float biasH = 0.5f * KAPPA * (b_ih[h] + b_hh[h]);
    const float bfc   = b_fc[0];

    float wfc_r[HH];
#pragma unroll
    for (int r = 0; r < HH; ++r) wfc_r[r] = W_fc[r];

    h_lds[lane] = 0.0f;
    __syncthreads();

    const size_t xbase = (size_t)b * TT;
    float xv = x[xbase + lane];   // x values for chunk 0

    for (int c = 0; c < TT / CH; ++c) {
        const int cn = (c + 1) & (TT / CH - 1);      // wrapped prefetch (always in-bounds)
        float xv_next = x[xbase + cn * CH + lane];

#pragma unroll 8
        for (int tc = 0; tc < CH; ++tc) {
            // broadcast this step's scalar input to all lanes (SGPR path)
            float xt = __uint_as_float(
                __builtin_amdgcn_readlane(__float_as_uint(xv), tc));

            // 16 h values for this K-half: 4 broadcast ds_read_b128
            const float4* hp = (const float4*)&h_lds[p * 16];
            float4 a0 = hp[0], a1 = hp[1], a2 = hp[2], a3 = hp[3];

            float acc0 = fmaf(xt, wihH, biasH);   // xp seed (half per p)
            float acc1 = 0.0f, acc2 = 0.0f, acc3 = 0.0f;
            acc0 = fmaf(W2[ 0], a0.x, acc0);
            acc1 = fmaf(W2[ 1], a0.y, acc1);
            acc2 = fmaf(W2[ 2], a0.z, acc2);
            acc3 = fmaf(W2[ 3], a0.w, acc3);
            acc0 = fmaf(W2[ 4], a1.x, acc0);
            acc1 = fmaf(W2[ 5], a1.y, acc1);
            acc2 = fmaf(W2[ 6], a1.z, acc2);
            acc3 = fmaf(W2[ 7], a1.w, acc3);
            acc0 = fmaf(W2[ 8], a2.x, acc0);
            acc1 = fmaf(W2[ 9], a2.y, acc1);
            acc2 = fmaf(W2[10], a2.z, acc2);
            acc3 = fmaf(W2[11], a2.w, acc3);
            acc0 = fmaf(W2[12], a3.x, acc0);
            acc1 = fmaf(W2[13], a3.y, acc1);
            acc2 = fmaf(W2[14], a3.z, acc2);
            acc3 = fmaf(W2[15], a3.w, acc3);

            float dot = (acc0 + acc1) + (acc2 + acc3);
            dot += __shfl_xor(dot, 32);          // combine the two K-halves

            // h = tanh(a) = 1 - 2/(1 + 2^(2*log2e*a)); scaling pre-folded
            float e  = EXP2F(dot);
            float hn = fmaf(-2.0f, __builtin_amdgcn_rcpf(e + 1.0f), 1.0f);

            __builtin_amdgcn_wave_barrier();
            h_lds[lane]           = hn;   // wave-synchronous h update
            obuf[lane * 65 + tc]  = hn;   // stash for deferred W_fc reduce
            __builtin_amdgcn_wave_barrier();
        }

        // parallel reduction over h for the 64 timesteps of this chunk:
        // lane t computes sum_h obuf[h][t] * wfc[h]
        __builtin_amdgcn_wave_barrier();
        float s0 = 0.0f, s1 = 0.0f, s2 = 0.0f, s3 = 0.0f;
#pragma unroll
        for (int r = 0; r < HH; r += 4) {
            s0 = fmaf(obuf[(r + 0) * 65 + lane], wfc_r[r + 0], s0);
            s1 = fmaf(obuf[(r + 1) * 65 + lane], wfc_r[r + 1], s1);
            s2 = fmaf(obuf[(r + 2) * 65 + lane], wfc_r[r + 2], s2);
            s3 = fmaf(obuf[(r + 3) * 65 + lane], wfc_r[r + 3], s3);
        }
        out[xbase + c * CH + lane] = (s0 + s1) + (s2 + s3) + bfc;

        xv = xv_next;
        __builtin_amdgcn_wave_barrier();
    }
}

extern "C" void kernel_launch(void* const* d_in, const int* in_sizes, int n_in,
                              void* d_out, int out_size, void* d_ws, size_t ws_size,
                              hipStream_t stream) {
    const float* x    = (const float*)d_in[0];
    const float* W_ih = (const float*)d_in[1];
    const float* W_hh = (const float*)d_in[2];
    const float* b_ih = (const float*)d_in[3];
    const float* b_hh = (const float*)d_in[4];
    const float* W_fc = (const float*)d_in[5];
    const float* b_fc = (const float*)d_in[6];
    float* out = (float*)d_out;

    rnn_fused<<<NB, 64, 0, stream>>>(x, W_ih, W_hh, b_ih, b_hh, W_fc, b_fc, out);
}